// Round 2
// baseline (105.436 us; speedup 1.0000x reference)
//
#include <hip/hip_runtime.h>

// out[b] = clip( hardswish( dot(x[b,:], colsum(y)) ) + noise[b], -0.5, 0.5 )
// B = 8192 rows, F = 4096 features. Memory-bound: read x (128MB) + y (128MB).
//
// Round 1 lesson: 64-block colsum left 3/4 of the chip idle (101 us,
// latency-bound, 2.7% occupancy). Split colsum over a 2-D grid
// (4 column strips x NSLAB row slabs) for full-chip parallelism.

namespace {

constexpr int F = 4096;
constexpr int B = 8192;
constexpr int NSTRIP = 4;            // F / (256 threads * 4 floats)

__device__ __forceinline__ void f4_add(float4& a, const float4 b) {
    a.x += b.x; a.y += b.y; a.z += b.z; a.w += b.w;
}

// Phase A: block (strip s, slab p) sums rows [p*rows, (p+1)*rows) of
// column strip [s*1024, (s+1)*1024) into partial[p*F + s*1024 ...].
// 256 threads x float4 = 1024 cols. Fully coalesced 16B/lane loads.
__global__ __launch_bounds__(256) void colsum_partial_k(
    const float* __restrict__ y, float* __restrict__ partial, int rows_per_slab)
{
    const int s = blockIdx.x;            // column strip
    const int p = blockIdx.y;            // row slab
    const int t = threadIdx.x;
    const long row0 = (long)p * rows_per_slab;
    const int  c4   = s * 256 + t;       // float4 column index

    float4 acc = {0.f,0.f,0.f,0.f};
    for (int r = 0; r < rows_per_slab; ++r) {
        f4_add(acc, reinterpret_cast<const float4*>(y + (row0 + r) * F)[c4]);
    }
    reinterpret_cast<float4*>(partial + (long)p * F)[c4] = acc;
}

// Phase B: ysum[c] = sum_p partial[p*F + c]. Thread owns one column;
// consecutive threads -> consecutive c -> coalesced.
__global__ __launch_bounds__(256) void colsum_final_k(
    const float* __restrict__ partial, float* __restrict__ ysum, int nslab)
{
    const int c = blockIdx.x * 256 + threadIdx.x;
    float acc = 0.f;
    for (int p = 0; p < nslab; ++p) acc += partial[(long)p * F + c];
    ysum[c] = acc;
}

// Phase C: one block per row. dot(x[b,:], ysum) -> hardswish -> +noise -> clip.
__global__ __launch_bounds__(256) void rowdot_k(
    const float* __restrict__ x, const float* __restrict__ ysum,
    const float* __restrict__ noise, float* __restrict__ out)
{
    const int b = blockIdx.x;
    const int t = threadIdx.x;

    const float4* xrow = reinterpret_cast<const float4*>(x + (long)b * F);
    const float4* ys   = reinterpret_cast<const float4*>(ysum);

    float p = 0.f;
#pragma unroll
    for (int g = 0; g < 4; ++g) {
        float4 xv = xrow[g * 256 + t];
        float4 yv = ys[g * 256 + t];
        p += xv.x * yv.x + xv.y * yv.y + xv.z * yv.z + xv.w * yv.w;
    }

    // wave-64 down-reduce
#pragma unroll
    for (int off = 32; off > 0; off >>= 1) p += __shfl_down(p, off);

    __shared__ float wsum[4];
    if ((t & 63) == 0) wsum[t >> 6] = p;
    __syncthreads();

    if (t == 0) {
        float s = wsum[0] + wsum[1] + wsum[2] + wsum[3];
        float h = s * fminf(fmaxf(s + 3.0f, 0.0f), 6.0f) * (1.0f / 6.0f);
        float r = h + noise[b];               // logsumexp(singleton) == identity
        out[b] = fminf(fmaxf(r, -0.5f), 0.5f);
    }
}

} // namespace

extern "C" void kernel_launch(void* const* d_in, const int* in_sizes, int n_in,
                              void* d_out, int out_size, void* d_ws, size_t ws_size,
                              hipStream_t stream)
{
    const float* x     = (const float*)d_in[0];   // (B, F)
    const float* y     = (const float*)d_in[1];   // (B, F)
    const float* noise = (const float*)d_in[2];   // (B, 1)
    float*       out   = (float*)d_out;           // (B, 1) fp32

    // Workspace: [nslab * F floats partials][F floats ysum]
    int nslab = 256;
    while (nslab > 1 && (size_t)(nslab + 1) * F * sizeof(float) > ws_size) nslab >>= 1;
    float* partial = (float*)d_ws;
    float* ysum    = partial + (size_t)nslab * F;
    const int rows_per_slab = B / nslab;

    dim3 gridA(NSTRIP, nslab);
    colsum_partial_k<<<gridA,    256, 0, stream>>>(y, partial, rows_per_slab);
    colsum_final_k  <<<F / 256,  256, 0, stream>>>(partial, ysum, nslab);
    rowdot_k        <<<B,        256, 0, stream>>>(x, ysum, noise, out);
}